// Round 8
// baseline (22.971 us; speedup 1.0000x reference)
//
#include <hip/hip_runtime.h>

#define HEADN   2000
#define NF4     500      // float4 per row head
#define NSAMP   100
#define KC      10
#define CLIPV   20.0f
#define BATCH   2048
#define NCLASS  50000
#define TAILSCL 480.0f   // (50000-2000)/100

// clang native vector type — __builtin_nontemporal_load requires this
typedef float vf4 __attribute__((ext_vector_type(4)));

__device__ __forceinline__ float clipf(float x) {
    return fminf(fmaxf(x, -CLIPV), CLIPV);
}

// fast softplus via hardware v_exp_f32/v_log_f32; x pre-clipped to [-20,20]
__device__ __forceinline__ float sp(float x) {
    return __logf(1.0f + __expf(x));
}

__device__ __forceinline__ float sp4(vf4 v) {
    return (sp(clipf(v.x)) + sp(clipf(v.y))) + (sp(clipf(v.z)) + sp(clipf(v.w)));
}

// single-touch data: nontemporal loads (measured neutral, kept — no alloc)
__device__ __forceinline__ vf4 ntload4(const vf4* p) {
    return __builtin_nontemporal_load(p);
}

// One row per WAVE: 512 blocks x 4 waves. Single kernel: per-block partial
// (sum of 4 row losses / BATCH) accumulated into out[0] via one atomicAdd
// per block. No fences (atomicAdd is device-scope; order-rounding jitter
// <= ~10 abs on a ~45k loss vs 803 threshold). out[0] zeroed each call by
// a capturable hipMemsetAsync in kernel_launch.
__global__ __launch_bounds__(256) void row_loss_wave(
        const float* __restrict__ logits,
        const int*   __restrict__ cand,
        const int*   __restrict__ samp,
        float*       __restrict__ out)
{
    const int tid  = threadIdx.x;
    const int lane = tid & 63;
    const int w    = tid >> 6;
    const int row  = blockIdx.x * 4 + w;
    const float* lg = logits + (size_t)row * NCLASS;

    // ---- issue the gather chains first (longest latency) ----
    const int  s0i  = samp[lane];                            // lanes 0..63
    const bool s1a  = lane < NSAMP - 64;                     // lanes 0..35
    const int  s1i  = samp[s1a ? (lane + 64) : lane];
    const int  col0 = HEADN + s0i;
    const int  col1 = HEADN + s1i;
    const float sv0 = __builtin_nontemporal_load(lg + col0);
    const float sv1 = __builtin_nontemporal_load(lg + col1);

    const int cl = (lane < KC) ? cand[row * KC + lane] : -1;
    const float cval = (cl >= 0) ? __builtin_nontemporal_load(lg + cl) : 0.f;

    // ---- head: all 8 rounds of float4 loads issued back-to-back ----
    const vf4* lg4 = (const vf4*)lg;
    const bool t7 = lane < NF4 - 448;                        // lanes 0..51
    const vf4 v0 = ntload4(lg4 + lane);
    const vf4 v1 = ntload4(lg4 + lane + 64);
    const vf4 v2 = ntload4(lg4 + lane + 128);
    const vf4 v3 = ntload4(lg4 + lane + 192);
    const vf4 v4 = ntload4(lg4 + lane + 256);
    const vf4 v5 = ntload4(lg4 + lane + 320);
    const vf4 v6 = ntload4(lg4 + lane + 384);
    const vf4 v7 = ntload4(lg4 + (t7 ? (lane + 448) : lane));

    // ---- candidate broadcast ----
    const int c0 = __shfl(cl, 0), c1 = __shfl(cl, 1), c2 = __shfl(cl, 2),
              c3 = __shfl(cl, 3), c4 = __shfl(cl, 4), c5 = __shfl(cl, 5),
              c6 = __shfl(cl, 6), c7 = __shfl(cl, 7), c8 = __shfl(cl, 8),
              c9 = __shfl(cl, 9);

    // ---- head softplus (dual accumulators) ----
    float acc0 = sp4(v0) + sp4(v2);
    float acc1 = sp4(v1) + sp4(v3);
    acc0 += sp4(v4) + sp4(v6);
    acc1 += sp4(v5);
    if (t7) acc1 += sp4(v7);

    // ---- sampled tail: skip candidate columns ----
    {
        bool isc = (col0 == c0) | (col0 == c1) | (col0 == c2) | (col0 == c3) |
                   (col0 == c4) | (col0 == c5) | (col0 == c6) | (col0 == c7) |
                   (col0 == c8) | (col0 == c9);
        if (!isc) acc0 += TAILSCL * sp(clipf(sv0));
    }
    if (s1a) {
        bool isc = (col1 == c0) | (col1 == c1) | (col1 == c2) | (col1 == c3) |
                   (col1 == c4) | (col1 == c5) | (col1 == c6) | (col1 == c7) |
                   (col1 == c8) | (col1 == c9);
        if (!isc) acc1 += TAILSCL * sp(clipf(sv1));
    }

    // ---- candidates: dedupe (dups collapse under .max in the ref) ----
    float candSum = 0.f, candCnt = 0.f;
    if (cl >= 0 && lane < KC) {
        bool distinct = true;
        if (lane > 0 && c0 == cl) distinct = false;
        if (lane > 1 && c1 == cl) distinct = false;
        if (lane > 2 && c2 == cl) distinct = false;
        if (lane > 3 && c3 == cl) distinct = false;
        if (lane > 4 && c4 == cl) distinct = false;
        if (lane > 5 && c5 == cl) distinct = false;
        if (lane > 6 && c6 == cl) distinct = false;
        if (lane > 7 && c7 == cl) distinct = false;
        if (lane > 8 && c8 == cl) distinct = false;
        if (distinct) {
            float x = clipf(cval);
            candSum = x;
            candCnt = 1.f;
            if (cl < HEADN) acc0 -= sp(x);   // masked out of term2
        }
    }

    // ---- 64-lane butterfly reduce (3 values) ----
    float acc = acc0 + acc1;
    #pragma unroll
    for (int off = 32; off > 0; off >>= 1) {
        acc     += __shfl_xor(acc, off);
        candSum += __shfl_xor(candSum, off);
        candCnt += __shfl_xor(candCnt, off);
    }

    // ---- per-block combine (4 row losses) -> ONE atomic per block ----
    __shared__ float sA[4];
    if (lane == 0) {
        float avg = candSum / fmaxf(candCnt, 1.f);
        sA[w] = (sp(-avg) + acc) * (1.0f / (float)BATCH);
    }
    __syncthreads();
    if (tid == 0) {
        atomicAdd(out, (sA[0] + sA[1]) + (sA[2] + sA[3]));
    }
}

extern "C" void kernel_launch(void* const* d_in, const int* in_sizes, int n_in,
                              void* d_out, int out_size, void* d_ws, size_t ws_size,
                              hipStream_t stream) {
    const float* logits = (const float*)d_in[0];
    const int*   cand   = (const int*)d_in[1];
    const int*   samp   = (const int*)d_in[2];
    float* out = (float*)d_out;

    // zero the accumulator every call (graph-capturable, deterministic)
    hipMemsetAsync(out, 0, sizeof(float), stream);
    row_loss_wave<<<BATCH / 4, 256, 0, stream>>>(logits, cand, samp, out);
}

// Round 9
// 15.451 us; speedup vs baseline: 1.4867x; 1.4867x over previous
//
#include <hip/hip_runtime.h>

#define HEADN   2000
#define NSAMP   100
#define KC      10
#define CLIPV   20.0f
#define BATCH   2048
#define NCLASS  50000
#define TAILSCL 480.0f   // (50000-2000)/100

__device__ __forceinline__ float clipf(float x) {
    return fminf(fmaxf(x, -CLIPV), CLIPV);
}

// fast softplus(x) = log(1+exp(x)) via hardware v_exp_f32 / v_log_f32.
// x pre-clipped to [-20,20]: 1+exp(x) in [1, 4.9e8]; abs error <= 2e-9 at
// x=-20 (threshold is 803 absolute), rel error ~1e-7 elsewhere.
__device__ __forceinline__ float sp(float x) {
    return __logf(1.0f + __expf(x));
}

// One row per WAVE: 512 blocks x 4 waves, no __syncthreads, no LDS.
// Measured best structure (round 3: 15.65 us). Fusion variants (fence-based
// last-block, per-block atomicAdd) both regressed; occupancy variants
// (2/4 waves per row) neutral; nontemporal loads neutral.
__global__ __launch_bounds__(256) void row_loss_wave(
        const float* __restrict__ logits,
        const int*   __restrict__ cand,
        const int*   __restrict__ samp,
        float*       __restrict__ row_out)
{
    const int tid  = threadIdx.x;
    const int lane = tid & 63;
    const int row  = blockIdx.x * 4 + (tid >> 6);
    const float* lg = logits + (size_t)row * NCLASS;

    // ---- candidates: lanes 0..9 load, broadcast to named regs ----
    const int cl = (lane < KC) ? cand[row * KC + lane] : -1;
    const int c0 = __shfl(cl, 0), c1 = __shfl(cl, 1), c2 = __shfl(cl, 2),
              c3 = __shfl(cl, 3), c4 = __shfl(cl, 4), c5 = __shfl(cl, 5),
              c6 = __shfl(cl, 6), c7 = __shfl(cl, 7), c8 = __shfl(cl, 8),
              c9 = __shfl(cl, 9);

    float candSum = 0.f, candCnt = 0.f, acc = 0.f;

    // ---- Phase A: distinct valid candidates (dups collapse under .max) ----
    if (lane < KC && cl >= 0) {
        bool distinct = true;
        if (lane > 0 && c0 == cl) distinct = false;
        if (lane > 1 && c1 == cl) distinct = false;
        if (lane > 2 && c2 == cl) distinct = false;
        if (lane > 3 && c3 == cl) distinct = false;
        if (lane > 4 && c4 == cl) distinct = false;
        if (lane > 5 && c5 == cl) distinct = false;
        if (lane > 6 && c6 == cl) distinct = false;
        if (lane > 7 && c7 == cl) distinct = false;
        if (lane > 8 && c8 == cl) distinct = false;
        if (distinct) {
            float x = clipf(lg[cl]);
            candSum = x;
            candCnt = 1.f;
            if (cl < HEADN) acc -= sp(x);   // masked out of term2
        }
    }

    // ---- Phase B: head softplus sum, 500 float4 per row over 64 lanes ----
    const float4* lg4 = (const float4*)lg;
    #pragma unroll
    for (int k = 0; k < 7; ++k) {           // i = lane..lane+384, all < 500
        float4 v = lg4[lane + 64 * k];
        acc += sp(clipf(v.x)) + sp(clipf(v.y)) + sp(clipf(v.z)) + sp(clipf(v.w));
    }
    {
        int i = lane + 448;                 // tail: lanes 0..51
        if (i < HEADN / 4) {
            float4 v = lg4[i];
            acc += sp(clipf(v.x)) + sp(clipf(v.y)) + sp(clipf(v.z)) + sp(clipf(v.w));
        }
    }

    // ---- Phase C: 100 sampled tail cols, 2 rounds over 64 lanes ----
    {
        const int col = HEADN + samp[lane];             // lanes 0..63
        bool isc = (col == c0) | (col == c1) | (col == c2) | (col == c3) |
                   (col == c4) | (col == c5) | (col == c6) | (col == c7) |
                   (col == c8) | (col == c9);
        if (!isc) acc += TAILSCL * sp(clipf(lg[col]));
    }
    if (lane < NSAMP - 64) {                            // lanes 0..35
        const int col = HEADN + samp[lane + 64];
        bool isc = (col == c0) | (col == c1) | (col == c2) | (col == c3) |
                   (col == c4) | (col == c5) | (col == c6) | (col == c7) |
                   (col == c8) | (col == c9);
        if (!isc) acc += TAILSCL * sp(clipf(lg[col]));
    }

    // ---- 64-lane butterfly reduce (3 values) ----
    #pragma unroll
    for (int off = 32; off > 0; off >>= 1) {
        candSum += __shfl_xor(candSum, off);
        candCnt += __shfl_xor(candCnt, off);
        acc     += __shfl_xor(acc, off);
    }

    if (lane == 0) {
        float avg = candSum / fmaxf(candCnt, 1.f);
        row_out[row] = sp(-avg) + acc;      // psi(avg) + term2 + term3
    }
}

__global__ __launch_bounds__(256) void mean_kernel(
        const float* __restrict__ row, float* __restrict__ out)
{
    const int tid = threadIdx.x;
    const float4* r4 = (const float4*)row;
    float s = 0.f;
    #pragma unroll
    for (int k = 0; k < BATCH / 4 / 256; ++k) {     // 2 float4 per thread
        float4 v = r4[tid + 256 * k];
        s += v.x + v.y + v.z + v.w;
    }
    #pragma unroll
    for (int off = 32; off > 0; off >>= 1) s += __shfl_xor(s, off);
    __shared__ float sw[4];
    if ((tid & 63) == 0) sw[tid >> 6] = s;
    __syncthreads();
    if (tid == 0) out[0] = (sw[0] + sw[1] + sw[2] + sw[3]) / (float)BATCH;
}

extern "C" void kernel_launch(void* const* d_in, const int* in_sizes, int n_in,
                              void* d_out, int out_size, void* d_ws, size_t ws_size,
                              hipStream_t stream) {
    const float* logits = (const float*)d_in[0];
    const int*   cand   = (const int*)d_in[1];
    const int*   samp   = (const int*)d_in[2];
    float* row_out = (float*)d_ws;          // BATCH floats of scratch
    float* out     = (float*)d_out;

    row_loss_wave<<<BATCH / 4, 256, 0, stream>>>(logits, cand, samp, row_out);
    mean_kernel<<<1, 256, 0, stream>>>(row_out, out);
}